// Round 1
// baseline (102.433 us; speedup 1.0000x reference)
//
#include <hip/hip_runtime.h>
#include <cmath>

// Peaks3d: out[b,c,d,h,w] = relu( sum_k w[k] * (sum_c' x[b,c',d+k-3,h,w]) )
// Identical across output channel c (kernel weight same for every (c_out,c_in)).
// B=4, C=4, D=24, H=W=384. fp32 in/out.

#define DD 24
#define CC 4
#define HW4 36864   // 384*384/4 float4 columns per (b,c,d) plane

struct W7 { float w[7]; };

__global__ __launch_bounds__(64) void peaks3d_kernel(const float4* __restrict__ x,
                                                     float4* __restrict__ out,
                                                     W7 wt) {
    const int col = blockIdx.x * 64 + threadIdx.x;   // 0..36863
    const int b   = blockIdx.y;                      // 0..3
    const size_t base = (size_t)b * CC * DD * HW4 + col;
    const float4* xb = x + base;
    float4*       ob = out + base;

    // ---- channel sum: s[d] = sum_c x[b,c,d,col] ----
    float4 s[DD];
#pragma unroll
    for (int d = 0; d < DD; ++d) {
        float4 a0 = xb[(size_t)(0 * DD + d) * HW4];
        float4 a1 = xb[(size_t)(1 * DD + d) * HW4];
        float4 a2 = xb[(size_t)(2 * DD + d) * HW4];
        float4 a3 = xb[(size_t)(3 * DD + d) * HW4];
        s[d].x = (a0.x + a1.x) + (a2.x + a3.x);
        s[d].y = (a0.y + a1.y) + (a2.y + a3.y);
        s[d].z = (a0.z + a1.z) + (a2.z + a3.z);
        s[d].w = (a0.w + a1.w) + (a2.w + a3.w);
    }

    // ---- depth conv (cross-correlation, zero pad 3) + ReLU + broadcast ----
#pragma unroll
    for (int d = 0; d < DD; ++d) {
        float ax = 0.f, ay = 0.f, az = 0.f, aw = 0.f;
#pragma unroll
        for (int k = 0; k < 7; ++k) {
            const int j = d + k - 3;           // compile-time after unroll
            if (j >= 0 && j < DD) {
                const float c = wt.w[k];
                ax += c * s[j].x;
                ay += c * s[j].y;
                az += c * s[j].z;
                aw += c * s[j].w;
            }
        }
        float4 r;
        r.x = fmaxf(ax, 0.f);
        r.y = fmaxf(ay, 0.f);
        r.z = fmaxf(az, 0.f);
        r.w = fmaxf(aw, 0.f);
#pragma unroll
        for (int c = 0; c < CC; ++c)
            ob[(size_t)(c * DD + d) * HW4] = r;
    }
}

extern "C" void kernel_launch(void* const* d_in, const int* in_sizes, int n_in,
                              void* d_out, int out_size, void* d_ws, size_t ws_size,
                              hipStream_t stream) {
    const float4* x   = (const float4*)d_in[0];
    float4*       out = (float4*)d_out;

    // Faithful replication of the reference weight construction (double prec).
    // x = linspace(-9, 10, 7); g = N(0,1.5) pdf; w = g*(x^2/s^4 - 1)/s^2;
    // w -= mean(w); w /= sum(w*x^2)/2; w = -w.
    W7 wt;
    {
        const double S = 1.5;
        double xs[7], w[7];
        double mean = 0.0;
        for (int i = 0; i < 7; ++i) {
            xs[i] = -9.0 + (double)i * (19.0 / 6.0);
            double g = exp(-(xs[i] * xs[i]) / (2.0 * S * S)) /
                       (sqrt(2.0 * M_PI) * S);
            w[i] = g * (xs[i] * xs[i] / (S * S * S * S) - 1.0) / (S * S);
            mean += w[i];
        }
        mean /= 7.0;
        double norm = 0.0;
        for (int i = 0; i < 7; ++i) {
            w[i] -= mean;
            norm += w[i] * xs[i] * xs[i];
        }
        norm *= 0.5;
        for (int i = 0; i < 7; ++i) wt.w[i] = (float)(-(w[i] / norm));
    }

    dim3 grid(576, 4);   // 576*64 = 36864 float4 columns; y = batch
    peaks3d_kernel<<<grid, 64, 0, stream>>>(x, out, wt);
}

// Round 2
// 83.337 us; speedup vs baseline: 1.2291x; 1.2291x over previous
//
#include <hip/hip_runtime.h>
#include <cmath>

// Peaks3d: out[b,c,d,h,w] = relu( sum_k w[k] * (sum_c' x[b,c',d+k-3,h,w]) )
// Identical across output channel c. B=4, C=4, D=24, H=W=384. fp32 in/out.
//
// Memory-bound: 226.5 MB read + 226.5 MB write, exactly once each.
// All streams are zero-reuse -> nontemporal (nt) loads/stores to bypass
// L2 allocation thrash from 192 concurrent streams per wave.

#define DD 24
#define CC 4
#define HW4 36864   // 384*384/4 float4 columns per (b,c,d) plane

typedef float f4 __attribute__((ext_vector_type(4)));

struct W7 { float w[7]; };

__global__ __launch_bounds__(256) void peaks3d_kernel(const f4* __restrict__ x,
                                                      f4* __restrict__ out,
                                                      W7 wt) {
    const int col = blockIdx.x * 256 + threadIdx.x;  // 0..36863
    const int b   = blockIdx.y;                      // 0..3
    const size_t base = (size_t)b * CC * DD * HW4 + col;
    const f4* xb = x + base;
    f4*       ob = out + base;

    // ---- channel sum: s[d] = sum_c x[b,c,d,col] ----
    f4 s[DD];
#pragma unroll
    for (int d = 0; d < DD; ++d) {
        f4 a0 = __builtin_nontemporal_load(xb + (size_t)(0 * DD + d) * HW4);
        f4 a1 = __builtin_nontemporal_load(xb + (size_t)(1 * DD + d) * HW4);
        f4 a2 = __builtin_nontemporal_load(xb + (size_t)(2 * DD + d) * HW4);
        f4 a3 = __builtin_nontemporal_load(xb + (size_t)(3 * DD + d) * HW4);
        s[d] = (a0 + a1) + (a2 + a3);
    }

    // ---- depth conv (cross-correlation, zero pad 3) + ReLU + broadcast ----
#pragma unroll
    for (int d = 0; d < DD; ++d) {
        f4 acc = (f4)0.0f;
#pragma unroll
        for (int k = 0; k < 7; ++k) {
            const int j = d + k - 3;           // compile-time after unroll
            if (j >= 0 && j < DD)
                acc += wt.w[k] * s[j];
        }
        f4 r;
        r.x = fmaxf(acc.x, 0.f);
        r.y = fmaxf(acc.y, 0.f);
        r.z = fmaxf(acc.z, 0.f);
        r.w = fmaxf(acc.w, 0.f);
#pragma unroll
        for (int c = 0; c < CC; ++c)
            __builtin_nontemporal_store(r, ob + (size_t)(c * DD + d) * HW4);
    }
}

extern "C" void kernel_launch(void* const* d_in, const int* in_sizes, int n_in,
                              void* d_out, int out_size, void* d_ws, size_t ws_size,
                              hipStream_t stream) {
    const f4* x   = (const f4*)d_in[0];
    f4*       out = (f4*)d_out;

    // Faithful replication of the reference weight construction (double prec).
    W7 wt;
    {
        const double S = 1.5;
        double xs[7], w[7];
        double mean = 0.0;
        for (int i = 0; i < 7; ++i) {
            xs[i] = -9.0 + (double)i * (19.0 / 6.0);
            double g = exp(-(xs[i] * xs[i]) / (2.0 * S * S)) /
                       (sqrt(2.0 * M_PI) * S);
            w[i] = g * (xs[i] * xs[i] / (S * S * S * S) - 1.0) / (S * S);
            mean += w[i];
        }
        mean /= 7.0;
        double norm = 0.0;
        for (int i = 0; i < 7; ++i) {
            w[i] -= mean;
            norm += w[i] * xs[i] * xs[i];
        }
        norm *= 0.5;
        for (int i = 0; i < 7; ++i) wt.w[i] = (float)(-(w[i] / norm));
    }

    dim3 grid(HW4 / 256, 4);   // 144 x 4 blocks of 256 threads
    peaks3d_kernel<<<grid, 256, 0, stream>>>(x, out, wt);
}

// Round 3
// 78.147 us; speedup vs baseline: 1.3108x; 1.0664x over previous
//
#include <hip/hip_runtime.h>
#include <cmath>

// Peaks3d: out[b,c,d,h,w] = relu( sum_k w[k] * (sum_c' x[b,c',d+k-3,h,w]) )
// Identical across output channel c. B=4, C=4, D=24, H=W=384. fp32 in/out.
//
// Memory-bound: 226.5 MB read + 226.5 MB write, exactly once each.
// nt loads/stores: zero-reuse streams, bypass L2 allocation (R1: +23%).
// 64-thread blocks, 2304 blocks = exactly 9 blocks/CU, uniform work ->
// no scheduling tail (R1's 576x256 grid was 2.25 blocks/CU, uneven).

#define DD 24
#define CC 4
#define HW4 36864   // 384*384/4 float4 columns per (b,c,d) plane

typedef float f4 __attribute__((ext_vector_type(4)));

struct W7 { float w[7]; };

__global__ __launch_bounds__(64, 3) void peaks3d_kernel(const f4* __restrict__ x,
                                                        f4* __restrict__ out,
                                                        W7 wt) {
    const int col = blockIdx.x * 64 + threadIdx.x;   // 0..36863
    const int b   = blockIdx.y;                      // 0..3
    const size_t base = (size_t)b * CC * DD * HW4 + col;
    const f4* xb = x + base;
    f4*       ob = out + base;

    // ---- channel sum: s[d] = sum_c x[b,c,d,col] ----
    f4 s[DD];
#pragma unroll
    for (int d = 0; d < DD; ++d) {
        f4 a0 = __builtin_nontemporal_load(xb + (size_t)(0 * DD + d) * HW4);
        f4 a1 = __builtin_nontemporal_load(xb + (size_t)(1 * DD + d) * HW4);
        f4 a2 = __builtin_nontemporal_load(xb + (size_t)(2 * DD + d) * HW4);
        f4 a3 = __builtin_nontemporal_load(xb + (size_t)(3 * DD + d) * HW4);
        s[d] = (a0 + a1) + (a2 + a3);
    }

    // ---- depth conv (cross-correlation, zero pad 3) + ReLU + broadcast ----
#pragma unroll
    for (int d = 0; d < DD; ++d) {
        f4 acc = (f4)0.0f;
#pragma unroll
        for (int k = 0; k < 7; ++k) {
            const int j = d + k - 3;           // compile-time after unroll
            if (j >= 0 && j < DD)
                acc += wt.w[k] * s[j];
        }
        f4 r;
        r.x = fmaxf(acc.x, 0.f);
        r.y = fmaxf(acc.y, 0.f);
        r.z = fmaxf(acc.z, 0.f);
        r.w = fmaxf(acc.w, 0.f);
#pragma unroll
        for (int c = 0; c < CC; ++c)
            __builtin_nontemporal_store(r, ob + (size_t)(c * DD + d) * HW4);
    }
}

extern "C" void kernel_launch(void* const* d_in, const int* in_sizes, int n_in,
                              void* d_out, int out_size, void* d_ws, size_t ws_size,
                              hipStream_t stream) {
    const f4* x   = (const f4*)d_in[0];
    f4*       out = (f4*)d_out;

    // Faithful replication of the reference weight construction (double prec).
    W7 wt;
    {
        const double S = 1.5;
        double xs[7], w[7];
        double mean = 0.0;
        for (int i = 0; i < 7; ++i) {
            xs[i] = -9.0 + (double)i * (19.0 / 6.0);
            double g = exp(-(xs[i] * xs[i]) / (2.0 * S * S)) /
                       (sqrt(2.0 * M_PI) * S);
            w[i] = g * (xs[i] * xs[i] / (S * S * S * S) - 1.0) / (S * S);
            mean += w[i];
        }
        mean /= 7.0;
        double norm = 0.0;
        for (int i = 0; i < 7; ++i) {
            w[i] -= mean;
            norm += w[i] * xs[i] * xs[i];
        }
        norm *= 0.5;
        for (int i = 0; i < 7; ++i) wt.w[i] = (float)(-(w[i] / norm));
    }

    dim3 grid(HW4 / 64, 4);   // 576 x 4 = 2304 blocks of 64 threads = 9/CU
    peaks3d_kernel<<<grid, 64, 0, stream>>>(x, out, wt);
}